// Round 1
// baseline (163.644 us; speedup 1.0000x reference)
//
#include <hip/hip_runtime.h>

#define DEV __device__ __forceinline__

typedef __attribute__((ext_vector_type(8))) short short8v;
typedef __attribute__((ext_vector_type(4))) float f32x4;

DEV unsigned short bfr(float f) {                 // fp32 -> bf16 RNE (weights)
    unsigned u = __float_as_uint(f);
    return (unsigned short)((u + 0x7fffu + ((u >> 16) & 1u)) >> 16);
}
DEV short bft(float f) { return (short)(__float_as_uint(f) >> 16); } // truncate (activations)
DEV float bf2f(unsigned short h) { return __uint_as_float(((unsigned)h) << 16); }
DEV float frcp(float x) { return __builtin_amdgcn_rcpf(x); }
DEV float ftanh(float x) { float e = __expf(2.0f * x); return 1.0f - 2.0f * frcp(e + 1.0f); }

constexpr int NN = 4096, TT = 128, RING = 16;
#define MFMA32(a, b, c) __builtin_amdgcn_mfma_f32_16x16x32_bf16(a, b, c, 0, 0, 0)

// Decoupled producer/consumer, 16 waves (1024 thr), NO mid-kernel barriers.
// Wave 0 (scanner) free-runs the 127-step serial tmp recurrence, publishing
// bf16 tmp B-frags into a 16-slot LDS ring; it fences (lgkmcnt0) + bumps a
// 'head' counter every 2 steps, and every 8 steps polls a per-consumer
// progress array before reusing ring slots. Waves 1-15 (consumers) pull work
// by dynamic LDS-atomic ticket (perfect balance incl. the waves sharing
// SIMD0 with the scanner), poll head, then run phi. Message-passing safety:
// value-dependent poll -> data read issues after flag value known;
// __threadfence_block between data-write/flag-write and data-read/progress-
// write; "" memory asm stops the ring load being hoisted over the poll.
// Permuted-feature in-lane chaining retained from the previous version.

__global__ __launch_bounds__(1024) __attribute__((amdgpu_waves_per_eu(4)))
void wfa_kernel(
    const float* __restrict__ x,
    const float* __restrict__ e1w, const float* __restrict__ e1b,
    const float* __restrict__ e2w, const float* __restrict__ e2b,
    const float* __restrict__ A,
    const float* __restrict__ initw,
    const float* __restrict__ n1w, const float* __restrict__ n1b,
    const float* __restrict__ n2w, const float* __restrict__ n2b,
    const float* __restrict__ muw, const float* __restrict__ mub,
    const float* __restrict__ sgw, const float* __restrict__ sgb,
    const float* __restrict__ alw, const float* __restrict__ alb,
    float* __restrict__ out)
{
    __shared__ __align__(16) unsigned short enc_l[TT * 128];  // [t][n*8+d] bf16, 32KB
    __shared__ __align__(16) float x_l[16 * 130];             // [n][t]
    __shared__ __align__(16) short8v ring_l[RING][64];        // tmp frags, 16KB
    __shared__ __align__(16) float n1b_l[64], n2b_l[64], hb_l[48];
    __shared__ float part_l[16][16];
    __shared__ int head_l;     // items published by scanner
    __shared__ int ticket_l;   // next item index to hand out
    __shared__ int prog_l[15]; // per-consumer: all my ring reads < prog are done

    const int tid = threadIdx.x;
    const int wv = tid >> 6, lane = tid & 63;
    const int quad = lane >> 4, col = lane & 15;
    const int n0 = blockIdx.x * 16;
    const f32x4 z4 = {0.f, 0.f, 0.f, 0.f};

    // ---- stage x + biases + control ----
    for (int i = tid; i < 16 * TT; i += 1024)
        x_l[(i >> 7) * 130 + (i & 127)] = x[(n0 + (i >> 7)) * TT + (i & 127)];
    if (tid < 64) { n1b_l[tid] = n1b[tid]; n2b_l[tid] = n2b[tid]; }
    if (tid >= 64 && tid < 112) {
        const int i = tid - 64, mt = i >> 4, k = i & 15;
        hb_l[i] = (k < 10) ? ((mt == 0) ? mub[k] : (mt == 1) ? sgb[k] : alb[k]) : 0.f;
    }
    if (tid >= 112 && tid < 127) prog_l[tid - 112] = 0;
    if (tid == 127) { head_l = 0; ticket_l = 0; }

    __syncthreads();   // x_l + control ready

    // ---- encoder over 16 waves: wave handles t-tile (wv&7), sample-half (wv>>3) ----
    {
        float e1c[16], e1bc[16];
        #pragma unroll
        for (int kc = 0; kc < 2; ++kc)
            #pragma unroll
            for (int jj = 0; jj < 8; ++jj) {
                const int f = kc * 32 + (jj >> 2) * 16 + quad * 4 + (jj & 3);
                e1c[kc * 8 + jj] = e1w[f];
                e1bc[kc * 8 + jj] = e1b[f];
            }
        short8v E2A[2];   // A[m=d(col<8)][k=h feature, permuted]
        #pragma unroll
        for (int kc = 0; kc < 2; ++kc)
            #pragma unroll
            for (int jj = 0; jj < 8; ++jj)
                E2A[kc][jj] = (short)(col < 8
                    ? bfr(e2w[(kc * 32 + (jj >> 2) * 16 + quad * 4 + (jj & 3)) * 8 + col]) : 0);
        float e2bc[4];
        #pragma unroll
        for (int r = 0; r < 4; ++r) e2bc[r] = (quad < 2) ? e2b[quad * 4 + r] : 0.f;

        const int tbase = (wv & 7) * 16;
        const int nlo = (wv >> 3) * 8;
        #pragma unroll 1
        for (int nn = nlo; nn < nlo + 8; ++nn) {
            const float xs = x_l[nn * 130 + tbase + col];
            short8v eB[2];
            #pragma unroll
            for (int kc = 0; kc < 2; ++kc)
                #pragma unroll
                for (int jj = 0; jj < 8; ++jj)
                    eB[kc][jj] = bft(fmaxf(fmaf(xs, e1c[kc * 8 + jj], e1bc[kc * 8 + jj]), 0.f));
            f32x4 d = MFMA32(E2A[0], eB[0], z4);
            d = MFMA32(E2A[1], eB[1], d);
            if (quad < 2) {
                #pragma unroll
                for (int r = 0; r < 4; ++r)
                    enc_l[(tbase + col) * 128 + nn * 8 + quad * 4 + r] = bfr(ftanh(d[r] + e2bc[r]));
            }
        }
    }
    __syncthreads();   // enc_l ready; last block-wide barrier until epilogue

    if (wv == 0) {
        // =========================== SCANNER ===========================
        short8v A2f[16];   // out m=mt*16+col -> d=mt>>1, j-half=mt&1; k=i (permuted)
        #pragma unroll
        for (int mt = 0; mt < 16; ++mt)
            #pragma unroll
            for (int jj = 0; jj < 8; ++jj)
                A2f[mt][jj] = (short)bfr(
                    A[((jj >> 2) * 16 + quad * 4 + (jj & 3)) * 256 + (mt >> 1) * 32 + (mt & 1) * 16 + col]);

        short8v tmpB;
        #pragma unroll
        for (int jj = 0; jj < 8; ++jj)
            tmpB[jj] = (short)bfr(initw[(jj >> 2) * 16 + quad * 4 + (jj & 3)]);

        asm volatile("s_setprio 2");   // win SIMD arbitration vs co-resident consumers

        short8v e8c = *(const short8v*)&enc_l[0 * 128 + col * 8];  // enc[0] for t=1

        #pragma unroll 1
        for (int t = 0; t < TT; ++t) {
            if (t > 0) {
                // prefetch enc[t] (used at t+1); waited only at e8c=e8n
                const short8v e8n = *(const short8v*)&enc_l[t * 128 + col * 8];
                float ev[8];
                #pragma unroll
                for (int d = 0; d < 8; ++d) ev[d] = bf2f((unsigned short)e8c[d]);
                short8v nt;
                #pragma unroll
                for (int h = 0; h < 2; ++h) {
                    f32x4 D[8];
                    #pragma unroll
                    for (int d = 0; d < 8; ++d) D[d] = MFMA32(A2f[2 * d + h], tmpB, z4);
                    #pragma unroll
                    for (int r = 0; r < 4; ++r) {
                        float s = 0.f;
                        #pragma unroll
                        for (int d = 0; d < 8; ++d) s = fmaf(ev[d], D[d][r], s);
                        nt[h * 4 + r] = bft(s);
                    }
                }
                tmpB = nt;
                e8c = e8n;
            }
            ring_l[t & (RING - 1)][lane] = tmpB;
            if (t & 1) {
                __threadfence_block();                      // commit ring writes
                if (lane == 0) *(volatile int*)&head_l = t + 1;
            }
            if ((t & 7) == 7 && t >= 15 && t < 120) {
                // next 8 steps overwrite items t-15..t-8: need min(prog) >= t-7
                const int need = t - 7;
                while (true) {
                    int p = (lane < 15) ? *(volatile int*)&prog_l[lane] : (1 << 30);
                    #pragma unroll
                    for (int s = 1; s < 64; s <<= 1) {
                        const int q = __shfl_xor(p, s, 64);
                        p = (q < p) ? q : p;
                    }
                    if (p >= need) break;
                    __builtin_amdgcn_s_sleep(4);
                }
            }
        }
        if (lane < 16) part_l[0][lane] = 0.f;
    } else {
        // ========================== CONSUMERS ==========================
        short8v W1f[4];    // h1 out = mt*16+col, k = th feature (permuted)
        #pragma unroll
        for (int mt = 0; mt < 4; ++mt)
            #pragma unroll
            for (int jj = 0; jj < 8; ++jj)
                W1f[mt][jj] = (short)bfr(n1w[((jj >> 2) * 16 + quad * 4 + (jj & 3)) * 64 + mt * 16 + col]);
        short8v W2f[4][2];
        #pragma unroll
        for (int mt = 0; mt < 4; ++mt)
            #pragma unroll
            for (int kb = 0; kb < 2; ++kb)
                #pragma unroll
                for (int jj = 0; jj < 8; ++jj)
                    W2f[mt][kb][jj] = (short)bfr(
                        n2w[(kb * 32 + (jj >> 2) * 16 + quad * 4 + (jj & 3)) * 64 + mt * 16 + col]);
        short8v Whf[3][2]; // 0=mu,1=sig,2=alpha; out m = head idx (col<10)
        #pragma unroll
        for (int mt = 0; mt < 3; ++mt) {
            const float* Wh = (mt == 0) ? muw : (mt == 1) ? sgw : alw;
            #pragma unroll
            for (int kb = 0; kb < 2; ++kb)
                #pragma unroll
                for (int jj = 0; jj < 8; ++jj)
                    Whf[mt][kb][jj] = (short)(col < 10
                        ? bfr(Wh[(kb * 32 + (jj >> 2) * 16 + quad * 4 + (jj & 3)) * 10 + col]) : 0);
        }

        float res2 = 0.f;
        const float CST = 0.91893853320467274f;
        const int c = wv - 1;

        int t;
        if (lane == 0) { t = atomicAdd(&ticket_l, 1); *(volatile int*)&prog_l[c] = t; }
        t = __shfl(t, 0, 64);

        while (t < TT) {
            while (*(volatile int*)&head_l <= t) __builtin_amdgcn_s_sleep(1);
            asm volatile("" ::: "memory");   // don't hoist ring read above poll
            const short8v tf = ring_l[t & (RING - 1)][lane];
            __threadfence_block();           // ring read complete before prog bump
            int tn;
            if (lane == 0) { tn = atomicAdd(&ticket_l, 1); *(volatile int*)&prog_l[c] = tn; }
            tn = __shfl(tn, 0, 64);

            short8v thB;
            #pragma unroll
            for (int jj = 0; jj < 8; ++jj)
                thB[jj] = bft(ftanh(bf2f((unsigned short)tf[jj])));

            // h1 = relu(W1^T @ th + b1)   (bias as C operand)
            short8v h1B[2];
            #pragma unroll
            for (int mt = 0; mt < 4; ++mt) {
                const f32x4 cc = *(const f32x4*)&n1b_l[mt * 16 + quad * 4];
                const f32x4 d = MFMA32(W1f[mt], thB, cc);
                #pragma unroll
                for (int r = 0; r < 4; ++r)
                    h1B[mt >> 1][(mt & 1) * 4 + r] = bft(fmaxf(d[r], 0.f));
            }
            // h2 = relu(W2^T @ h1 + b2)
            short8v h2B[2];
            #pragma unroll
            for (int mt = 0; mt < 4; ++mt) {
                const f32x4 cc = *(const f32x4*)&n2b_l[mt * 16 + quad * 4];
                f32x4 d = MFMA32(W2f[mt][0], h1B[0], cc);
                d = MFMA32(W2f[mt][1], h1B[1], d);
                #pragma unroll
                for (int r = 0; r < 4; ++r)
                    h2B[mt >> 1][(mt & 1) * 4 + r] = bft(fmaxf(d[r], 0.f));
            }
            // heads; lane holds heads quad*4+r for sample col
            f32x4 hd[3];
            #pragma unroll
            for (int mt = 0; mt < 3; ++mt) {
                const f32x4 cc = *(const f32x4*)&hb_l[mt * 16 + quad * 4];
                f32x4 d = MFMA32(Whf[mt][0], h2B[0], cc);
                hd[mt] = MFMA32(Whf[mt][1], h2B[1], d);
            }
            // no-max logsumexp (terms O(1); underflow->0 == reference's 0)
            const float xt = x_l[col * 130 + t];
            float s1 = 0.f, s2 = 0.f;
            #pragma unroll
            for (int r = 0; r < 4; ++r) {
                const bool valid = (quad * 4 + r) < 10;
                const float mu = hd[0][r], sg = hd[1][r], la = hd[2][r];
                const float e1t = __expf(la);
                const float z = (xt - mu) * __expf(-sg);
                const float e2t = __expf(la - sg - fmaf(0.5f * z, z, CST));
                s1 += valid ? e1t : 0.f;
                s2 += valid ? e2t : 0.f;
            }
            s1 += __shfl_xor(s1, 16, 64);  s2 += __shfl_xor(s2, 16, 64);
            s1 += __shfl_xor(s1, 32, 64);  s2 += __shfl_xor(s2, 32, 64);
            res2 += __log2f(s2) - __log2f(s1);

            t = tn;
        }
        if (lane == 0) *(volatile int*)&prog_l[c] = 1 << 30;
        if (lane < 16) part_l[wv][lane] = res2;   // uniform across quads
    }

    __syncthreads();
    if (tid < 16) {
        float s = 0.f;
        #pragma unroll
        for (int w = 0; w < 16; ++w) s += part_l[w][tid];
        out[n0 + tid] = exp2f(s);
    }
}

extern "C" void kernel_launch(void* const* d_in, const int* in_sizes, int n_in,
                              void* d_out, int out_size, void* d_ws, size_t ws_size,
                              hipStream_t stream) {
    wfa_kernel<<<dim3(NN / 16), dim3(1024), 0, stream>>>(
        (const float*)d_in[0],  (const float*)d_in[1],  (const float*)d_in[2],
        (const float*)d_in[3],  (const float*)d_in[4],  (const float*)d_in[5],
        (const float*)d_in[6],  (const float*)d_in[7],  (const float*)d_in[8],
        (const float*)d_in[9],  (const float*)d_in[10], (const float*)d_in[11],
        (const float*)d_in[12], (const float*)d_in[13], (const float*)d_in[14],
        (const float*)d_in[15], (const float*)d_in[16], (float*)d_out);
}

// Round 2
// 161.228 us; speedup vs baseline: 1.0150x; 1.0150x over previous
//
#include <hip/hip_runtime.h>

#define DEV __device__ __forceinline__

typedef __attribute__((ext_vector_type(8))) short short8v;
typedef __attribute__((ext_vector_type(4))) float f32x4;

DEV unsigned short bfr(float f) {                 // fp32 -> bf16 RNE (weights)
    unsigned u = __float_as_uint(f);
    return (unsigned short)((u + 0x7fffu + ((u >> 16) & 1u)) >> 16);
}
DEV short bft(float f) { return (short)(__float_as_uint(f) >> 16); } // truncate (activations)
DEV float bf2f(unsigned short h) { return __uint_as_float(((unsigned)h) << 16); }
DEV float frcp(float x) { return __builtin_amdgcn_rcpf(x); }
DEV float ftanh(float x) { float e = __expf(2.0f * x); return 1.0f - 2.0f * frcp(e + 1.0f); }

constexpr int NN = 4096, TT = 128, RING = 16;
#define MFMA32(a, b, c) __builtin_amdgcn_mfma_f32_16x16x32_bf16(a, b, c, 0, 0, 0)

// Decoupled producer/consumer, 16 waves (1024 thr), NO mid-kernel barriers.
// Wave 0 (scanner) free-runs the 127-step serial tmp recurrence, publishing
// bf16 tmp B-frags into a 16-slot LDS ring; it fences (lgkmcnt0) + bumps a
// 'head' counter every 2 steps, and every 8 steps polls a per-consumer
// progress array before reusing ring slots. Waves 1-15 (consumers) pull work
// by dynamic LDS-atomic ticket (perfect balance incl. the waves sharing
// SIMD0 with the scanner), poll head, then run phi.
// R1 LESSON: amdgpu_waves_per_eu(4) (min only) let the compiler target
// 8 waves/EU -> 64-VGPR cap -> 43MB scratch spills (WRITE_SIZE 27.8MB).
// Grid=256 blocks on 256 CUs means 1 block/CU regardless; pin (4,4) so the
// register allocator gets the full 128-VGPR budget (code needs ~84).

__global__ __launch_bounds__(1024) __attribute__((amdgpu_waves_per_eu(4, 4)))
void wfa_kernel(
    const float* __restrict__ x,
    const float* __restrict__ e1w, const float* __restrict__ e1b,
    const float* __restrict__ e2w, const float* __restrict__ e2b,
    const float* __restrict__ A,
    const float* __restrict__ initw,
    const float* __restrict__ n1w, const float* __restrict__ n1b,
    const float* __restrict__ n2w, const float* __restrict__ n2b,
    const float* __restrict__ muw, const float* __restrict__ mub,
    const float* __restrict__ sgw, const float* __restrict__ sgb,
    const float* __restrict__ alw, const float* __restrict__ alb,
    float* __restrict__ out)
{
    __shared__ __align__(16) unsigned short enc_l[TT * 128];  // [t][n*8+d] bf16, 32KB
    __shared__ __align__(16) float x_l[16 * 130];             // [n][t]
    __shared__ __align__(16) short8v ring_l[RING][64];        // tmp frags, 16KB
    __shared__ __align__(16) float n1b_l[64], n2b_l[64], hb_l[48];
    __shared__ float part_l[16][16];
    __shared__ int head_l;     // items published by scanner
    __shared__ int ticket_l;   // next item index to hand out
    __shared__ int prog_l[15]; // per-consumer: all my ring reads < prog are done

    const int tid = threadIdx.x;
    const int wv = tid >> 6, lane = tid & 63;
    const int quad = lane >> 4, col = lane & 15;
    const int n0 = blockIdx.x * 16;
    const f32x4 z4 = {0.f, 0.f, 0.f, 0.f};

    // ---- stage x + biases + control ----
    for (int i = tid; i < 16 * TT; i += 1024)
        x_l[(i >> 7) * 130 + (i & 127)] = x[(n0 + (i >> 7)) * TT + (i & 127)];
    if (tid < 64) { n1b_l[tid] = n1b[tid]; n2b_l[tid] = n2b[tid]; }
    if (tid >= 64 && tid < 112) {
        const int i = tid - 64, mt = i >> 4, k = i & 15;
        hb_l[i] = (k < 10) ? ((mt == 0) ? mub[k] : (mt == 1) ? sgb[k] : alb[k]) : 0.f;
    }
    if (tid >= 112 && tid < 127) prog_l[tid - 112] = 0;
    if (tid == 127) { head_l = 0; ticket_l = 0; }

    __syncthreads();   // x_l + control ready

    // ---- encoder over 16 waves: wave handles t-tile (wv&7), sample-half (wv>>3) ----
    {
        float e1c[16], e1bc[16];
        #pragma unroll
        for (int kc = 0; kc < 2; ++kc)
            #pragma unroll
            for (int jj = 0; jj < 8; ++jj) {
                const int f = kc * 32 + (jj >> 2) * 16 + quad * 4 + (jj & 3);
                e1c[kc * 8 + jj] = e1w[f];
                e1bc[kc * 8 + jj] = e1b[f];
            }
        short8v E2A[2];   // A[m=d(col<8)][k=h feature, permuted]
        #pragma unroll
        for (int kc = 0; kc < 2; ++kc)
            #pragma unroll
            for (int jj = 0; jj < 8; ++jj)
                E2A[kc][jj] = (short)(col < 8
                    ? bfr(e2w[(kc * 32 + (jj >> 2) * 16 + quad * 4 + (jj & 3)) * 8 + col]) : 0);
        float e2bc[4];
        #pragma unroll
        for (int r = 0; r < 4; ++r) e2bc[r] = (quad < 2) ? e2b[quad * 4 + r] : 0.f;

        const int tbase = (wv & 7) * 16;
        const int nlo = (wv >> 3) * 8;
        #pragma unroll 1
        for (int nn = nlo; nn < nlo + 8; ++nn) {
            const float xs = x_l[nn * 130 + tbase + col];
            short8v eB[2];
            #pragma unroll
            for (int kc = 0; kc < 2; ++kc)
                #pragma unroll
                for (int jj = 0; jj < 8; ++jj)
                    eB[kc][jj] = bft(fmaxf(fmaf(xs, e1c[kc * 8 + jj], e1bc[kc * 8 + jj]), 0.f));
            f32x4 d = MFMA32(E2A[0], eB[0], z4);
            d = MFMA32(E2A[1], eB[1], d);
            if (quad < 2) {
                #pragma unroll
                for (int r = 0; r < 4; ++r)
                    enc_l[(tbase + col) * 128 + nn * 8 + quad * 4 + r] = bfr(ftanh(d[r] + e2bc[r]));
            }
        }
    }
    __syncthreads();   // enc_l ready; last block-wide barrier until epilogue

    if (wv == 0) {
        // =========================== SCANNER ===========================
        short8v A2f[16];   // out m=mt*16+col -> d=mt>>1, j-half=mt&1; k=i (permuted)
        #pragma unroll
        for (int mt = 0; mt < 16; ++mt)
            #pragma unroll
            for (int jj = 0; jj < 8; ++jj)
                A2f[mt][jj] = (short)bfr(
                    A[((jj >> 2) * 16 + quad * 4 + (jj & 3)) * 256 + (mt >> 1) * 32 + (mt & 1) * 16 + col]);

        short8v tmpB;
        #pragma unroll
        for (int jj = 0; jj < 8; ++jj)
            tmpB[jj] = (short)bfr(initw[(jj >> 2) * 16 + quad * 4 + (jj & 3)]);

        asm volatile("s_setprio 2");   // win SIMD arbitration vs co-resident consumers

        short8v e8c = *(const short8v*)&enc_l[0 * 128 + col * 8];  // enc[0] for t=1

        #pragma unroll 1
        for (int t = 0; t < TT; ++t) {
            if (t > 0) {
                // prefetch enc[t] (used at t+1); waited only at e8c=e8n
                const short8v e8n = *(const short8v*)&enc_l[t * 128 + col * 8];
                float ev[8];
                #pragma unroll
                for (int d = 0; d < 8; ++d) ev[d] = bf2f((unsigned short)e8c[d]);
                short8v nt;
                #pragma unroll
                for (int h = 0; h < 2; ++h) {
                    f32x4 D[8];
                    #pragma unroll
                    for (int d = 0; d < 8; ++d) D[d] = MFMA32(A2f[2 * d + h], tmpB, z4);
                    #pragma unroll
                    for (int r = 0; r < 4; ++r) {
                        float s = 0.f;
                        #pragma unroll
                        for (int d = 0; d < 8; ++d) s = fmaf(ev[d], D[d][r], s);
                        nt[h * 4 + r] = bft(s);
                    }
                }
                tmpB = nt;
                e8c = e8n;
            }
            ring_l[t & (RING - 1)][lane] = tmpB;
            if (t & 1) {
                __threadfence_block();                      // commit ring writes
                if (lane == 0) *(volatile int*)&head_l = t + 1;
            }
            if ((t & 7) == 7 && t >= 15 && t < 120) {
                // next 8 steps overwrite items t-15..t-8: need min(prog) >= t-7
                const int need = t - 7;
                while (true) {
                    int p = (lane < 15) ? *(volatile int*)&prog_l[lane] : (1 << 30);
                    #pragma unroll
                    for (int s = 1; s < 64; s <<= 1) {
                        const int q = __shfl_xor(p, s, 64);
                        p = (q < p) ? q : p;
                    }
                    if (p >= need) break;
                    __builtin_amdgcn_s_sleep(4);
                }
            }
        }
        if (lane < 16) part_l[0][lane] = 0.f;
    } else {
        // ========================== CONSUMERS ==========================
        short8v W1f[4];    // h1 out = mt*16+col, k = th feature (permuted)
        #pragma unroll
        for (int mt = 0; mt < 4; ++mt)
            #pragma unroll
            for (int jj = 0; jj < 8; ++jj)
                W1f[mt][jj] = (short)bfr(n1w[((jj >> 2) * 16 + quad * 4 + (jj & 3)) * 64 + mt * 16 + col]);
        short8v W2f[4][2];
        #pragma unroll
        for (int mt = 0; mt < 4; ++mt)
            #pragma unroll
            for (int kb = 0; kb < 2; ++kb)
                #pragma unroll
                for (int jj = 0; jj < 8; ++jj)
                    W2f[mt][kb][jj] = (short)bfr(
                        n2w[(kb * 32 + (jj >> 2) * 16 + quad * 4 + (jj & 3)) * 64 + mt * 16 + col]);
        short8v Whf[3][2]; // 0=mu,1=sig,2=alpha; out m = head idx (col<10)
        #pragma unroll
        for (int mt = 0; mt < 3; ++mt) {
            const float* Wh = (mt == 0) ? muw : (mt == 1) ? sgw : alw;
            #pragma unroll
            for (int kb = 0; kb < 2; ++kb)
                #pragma unroll
                for (int jj = 0; jj < 8; ++jj)
                    Whf[mt][kb][jj] = (short)(col < 10
                        ? bfr(Wh[(kb * 32 + (jj >> 2) * 16 + quad * 4 + (jj & 3)) * 10 + col]) : 0);
        }

        float res2 = 0.f;
        const float CST = 0.91893853320467274f;
        const int c = wv - 1;

        int t;
        if (lane == 0) { t = atomicAdd(&ticket_l, 1); *(volatile int*)&prog_l[c] = t; }
        t = __shfl(t, 0, 64);

        while (t < TT) {
            while (*(volatile int*)&head_l <= t) __builtin_amdgcn_s_sleep(1);
            asm volatile("" ::: "memory");   // don't hoist ring read above poll
            const short8v tf = ring_l[t & (RING - 1)][lane];
            __threadfence_block();           // ring read complete before prog bump
            int tn;
            if (lane == 0) { tn = atomicAdd(&ticket_l, 1); *(volatile int*)&prog_l[c] = tn; }
            tn = __shfl(tn, 0, 64);

            short8v thB;
            #pragma unroll
            for (int jj = 0; jj < 8; ++jj)
                thB[jj] = bft(ftanh(bf2f((unsigned short)tf[jj])));

            // h1 = relu(W1^T @ th + b1)   (bias as C operand)
            short8v h1B[2];
            #pragma unroll
            for (int mt = 0; mt < 4; ++mt) {
                const f32x4 cc = *(const f32x4*)&n1b_l[mt * 16 + quad * 4];
                const f32x4 d = MFMA32(W1f[mt], thB, cc);
                #pragma unroll
                for (int r = 0; r < 4; ++r)
                    h1B[mt >> 1][(mt & 1) * 4 + r] = bft(fmaxf(d[r], 0.f));
            }
            // h2 = relu(W2^T @ h1 + b2)
            short8v h2B[2];
            #pragma unroll
            for (int mt = 0; mt < 4; ++mt) {
                const f32x4 cc = *(const f32x4*)&n2b_l[mt * 16 + quad * 4];
                f32x4 d = MFMA32(W2f[mt][0], h1B[0], cc);
                d = MFMA32(W2f[mt][1], h1B[1], d);
                #pragma unroll
                for (int r = 0; r < 4; ++r)
                    h2B[mt >> 1][(mt & 1) * 4 + r] = bft(fmaxf(d[r], 0.f));
            }
            // heads; lane holds heads quad*4+r for sample col
            f32x4 hd[3];
            #pragma unroll
            for (int mt = 0; mt < 3; ++mt) {
                const f32x4 cc = *(const f32x4*)&hb_l[mt * 16 + quad * 4];
                f32x4 d = MFMA32(Whf[mt][0], h2B[0], cc);
                hd[mt] = MFMA32(Whf[mt][1], h2B[1], d);
            }
            // no-max logsumexp (terms O(1); underflow->0 == reference's 0)
            const float xt = x_l[col * 130 + t];
            float s1 = 0.f, s2 = 0.f;
            #pragma unroll
            for (int r = 0; r < 4; ++r) {
                const bool valid = (quad * 4 + r) < 10;
                const float mu = hd[0][r], sg = hd[1][r], la = hd[2][r];
                const float e1t = __expf(la);
                const float z = (xt - mu) * __expf(-sg);
                const float e2t = __expf(la - sg - fmaf(0.5f * z, z, CST));
                s1 += valid ? e1t : 0.f;
                s2 += valid ? e2t : 0.f;
            }
            s1 += __shfl_xor(s1, 16, 64);  s2 += __shfl_xor(s2, 16, 64);
            s1 += __shfl_xor(s1, 32, 64);  s2 += __shfl_xor(s2, 32, 64);
            res2 += __log2f(s2) - __log2f(s1);

            t = tn;
        }
        if (lane == 0) *(volatile int*)&prog_l[c] = 1 << 30;
        if (lane < 16) part_l[wv][lane] = res2;   // uniform across quads
    }

    __syncthreads();
    if (tid < 16) {
        float s = 0.f;
        #pragma unroll
        for (int w = 0; w < 16; ++w) s += part_l[w][tid];
        out[n0 + tid] = exp2f(s);
    }
}

extern "C" void kernel_launch(void* const* d_in, const int* in_sizes, int n_in,
                              void* d_out, int out_size, void* d_ws, size_t ws_size,
                              hipStream_t stream) {
    wfa_kernel<<<dim3(NN / 16), dim3(1024), 0, stream>>>(
        (const float*)d_in[0],  (const float*)d_in[1],  (const float*)d_in[2],
        (const float*)d_in[3],  (const float*)d_in[4],  (const float*)d_in[5],
        (const float*)d_in[6],  (const float*)d_in[7],  (const float*)d_in[8],
        (const float*)d_in[9],  (const float*)d_in[10], (const float*)d_in[11],
        (const float*)d_in[12], (const float*)d_in[13], (const float*)d_in[14],
        (const float*)d_in[15], (const float*)d_in[16], (float*)d_out);
}

// Round 3
// 155.937 us; speedup vs baseline: 1.0494x; 1.0339x over previous
//
#include <hip/hip_runtime.h>

#define DEV __device__ __forceinline__

typedef __attribute__((ext_vector_type(8))) short short8v;
typedef __attribute__((ext_vector_type(4))) float f32x4;

DEV unsigned short bfr(float f) {                 // fp32 -> bf16 RNE (weights)
    unsigned u = __float_as_uint(f);
    return (unsigned short)((u + 0x7fffu + ((u >> 16) & 1u)) >> 16);
}
DEV short bft(float f) { return (short)(__float_as_uint(f) >> 16); } // truncate (activations)
DEV float bf2f(unsigned short h) { return __uint_as_float(((unsigned)h) << 16); }
DEV float frcp(float x) { return __builtin_amdgcn_rcpf(x); }
DEV float ftanh(float x) { float e = __expf(2.0f * x); return 1.0f - 2.0f * frcp(e + 1.0f); }

constexpr int NN = 4096, TT = 128, RING = 32;
#define MFMA32(a, b, c) __builtin_amdgcn_mfma_f32_16x16x32_bf16(a, b, c, 0, 0, 0)

// Decoupled producer/consumer, 16 waves (1024 thr), NO mid-kernel barriers.
// Wave 0 (scanner) free-runs the 127-step serial tmp recurrence, publishing
// bf16 tmp B-frags into a 32-slot LDS ring; waves 1-15 (consumers) pull work
// by dynamic LDS-atomic ticket, poll 'head' with an ACQUIRE atomic load,
// then run phi.
// R2 LESSONS (both applied here):
//  (a) asm volatile("" ::: "memory") in the consumer loop re-triggered the
//      prior session's R8 pathology: 30-48MB scratch traffic (WRITE_SIZE
//      30MB vs 16KB of real output). Replaced by __hip_atomic_load ACQUIRE
//      on head_l -- orders the ring read without clobbering all memory.
//  (b) VGPR_Count pinned at 64 despite waves_per_eu(4,4): LDS 59KB let two
//      16-wave blocks fit per CU, so LLVM's LDS-derived occupancy target was
//      8 waves/EU -> 64-VGPR cap. Grid=256 on 256 CUs means 2 blocks/CU is
//      useless anyway; pad LDS past 80KB (ring 16->32 slots, x_l tail pad)
//      so only 1 block fits -> derived target 4 waves/EU -> 128-VGPR budget.

__global__ __launch_bounds__(1024) __attribute__((amdgpu_waves_per_eu(4, 4)))
void wfa_kernel(
    const float* __restrict__ x,
    const float* __restrict__ e1w, const float* __restrict__ e1b,
    const float* __restrict__ e2w, const float* __restrict__ e2b,
    const float* __restrict__ A,
    const float* __restrict__ initw,
    const float* __restrict__ n1w, const float* __restrict__ n1b,
    const float* __restrict__ n2w, const float* __restrict__ n2b,
    const float* __restrict__ muw, const float* __restrict__ mub,
    const float* __restrict__ sgw, const float* __restrict__ sgb,
    const float* __restrict__ alw, const float* __restrict__ alb,
    float* __restrict__ out)
{
    __shared__ __align__(16) unsigned short enc_l[TT * 128];  // [t][n*8+d] bf16, 32KB
    // x_l: [n][t] with +2300 tail pad: pushes block LDS to ~83KB so only ONE
    // 16-wave block fits per CU => compiler register budget = 128 VGPR (see (b)).
    __shared__ __align__(16) float x_l[16 * 130 + 2300];
    __shared__ __align__(16) short8v ring_l[RING][64];        // tmp frags, 32KB
    __shared__ __align__(16) float n1b_l[64], n2b_l[64], hb_l[48];
    __shared__ float part_l[16][16];
    __shared__ int head_l;     // items published by scanner
    __shared__ int ticket_l;   // next item index to hand out
    __shared__ int prog_l[15]; // per-consumer: all my ring reads < prog are done

    const int tid = threadIdx.x;
    const int wv = tid >> 6, lane = tid & 63;
    const int quad = lane >> 4, col = lane & 15;
    const int n0 = blockIdx.x * 16;
    const f32x4 z4 = {0.f, 0.f, 0.f, 0.f};

    // ---- stage x + biases + control ----
    for (int i = tid; i < 16 * TT; i += 1024)
        x_l[(i >> 7) * 130 + (i & 127)] = x[(n0 + (i >> 7)) * TT + (i & 127)];
    if (tid < 64) { n1b_l[tid] = n1b[tid]; n2b_l[tid] = n2b[tid]; }
    if (tid >= 64 && tid < 112) {
        const int i = tid - 64, mt = i >> 4, k = i & 15;
        hb_l[i] = (k < 10) ? ((mt == 0) ? mub[k] : (mt == 1) ? sgb[k] : alb[k]) : 0.f;
    }
    if (tid >= 112 && tid < 127) prog_l[tid - 112] = 0;
    if (tid == 127) { head_l = 0; ticket_l = 0; }

    __syncthreads();   // x_l + control ready

    // ---- encoder over 16 waves: wave handles t-tile (wv&7), sample-half (wv>>3) ----
    {
        float e1c[16], e1bc[16];
        #pragma unroll
        for (int kc = 0; kc < 2; ++kc)
            #pragma unroll
            for (int jj = 0; jj < 8; ++jj) {
                const int f = kc * 32 + (jj >> 2) * 16 + quad * 4 + (jj & 3);
                e1c[kc * 8 + jj] = e1w[f];
                e1bc[kc * 8 + jj] = e1b[f];
            }
        short8v E2A[2];   // A[m=d(col<8)][k=h feature, permuted]
        #pragma unroll
        for (int kc = 0; kc < 2; ++kc)
            #pragma unroll
            for (int jj = 0; jj < 8; ++jj)
                E2A[kc][jj] = (short)(col < 8
                    ? bfr(e2w[(kc * 32 + (jj >> 2) * 16 + quad * 4 + (jj & 3)) * 8 + col]) : 0);
        float e2bc[4];
        #pragma unroll
        for (int r = 0; r < 4; ++r) e2bc[r] = (quad < 2) ? e2b[quad * 4 + r] : 0.f;

        const int tbase = (wv & 7) * 16;
        const int nlo = (wv >> 3) * 8;
        #pragma unroll 1
        for (int nn = nlo; nn < nlo + 8; ++nn) {
            const float xs = x_l[nn * 130 + tbase + col];
            short8v eB[2];
            #pragma unroll
            for (int kc = 0; kc < 2; ++kc)
                #pragma unroll
                for (int jj = 0; jj < 8; ++jj)
                    eB[kc][jj] = bft(fmaxf(fmaf(xs, e1c[kc * 8 + jj], e1bc[kc * 8 + jj]), 0.f));
            f32x4 d = MFMA32(E2A[0], eB[0], z4);
            d = MFMA32(E2A[1], eB[1], d);
            if (quad < 2) {
                #pragma unroll
                for (int r = 0; r < 4; ++r)
                    enc_l[(tbase + col) * 128 + nn * 8 + quad * 4 + r] = bfr(ftanh(d[r] + e2bc[r]));
            }
        }
    }
    __syncthreads();   // enc_l ready; last block-wide barrier until epilogue

    if (wv == 0) {
        // =========================== SCANNER ===========================
        short8v A2f[16];   // out m=mt*16+col -> d=mt>>1, j-half=mt&1; k=i (permuted)
        #pragma unroll
        for (int mt = 0; mt < 16; ++mt)
            #pragma unroll
            for (int jj = 0; jj < 8; ++jj)
                A2f[mt][jj] = (short)bfr(
                    A[((jj >> 2) * 16 + quad * 4 + (jj & 3)) * 256 + (mt >> 1) * 32 + (mt & 1) * 16 + col]);

        short8v tmpB;
        #pragma unroll
        for (int jj = 0; jj < 8; ++jj)
            tmpB[jj] = (short)bfr(initw[(jj >> 2) * 16 + quad * 4 + (jj & 3)]);

        asm volatile("s_setprio 2");   // win SIMD arbitration vs co-resident consumers

        short8v e8c = *(const short8v*)&enc_l[0 * 128 + col * 8];  // enc[0] for t=1

        #pragma unroll 1
        for (int t = 0; t < TT; ++t) {
            if (t > 0) {
                // prefetch enc[t] (used at t+1); waited only at e8c=e8n
                const short8v e8n = *(const short8v*)&enc_l[t * 128 + col * 8];
                float ev[8];
                #pragma unroll
                for (int d = 0; d < 8; ++d) ev[d] = bf2f((unsigned short)e8c[d]);
                short8v nt;
                #pragma unroll
                for (int h = 0; h < 2; ++h) {
                    f32x4 D[8];
                    #pragma unroll
                    for (int d = 0; d < 8; ++d) D[d] = MFMA32(A2f[2 * d + h], tmpB, z4);
                    #pragma unroll
                    for (int r = 0; r < 4; ++r) {
                        float s = 0.f;
                        #pragma unroll
                        for (int d = 0; d < 8; ++d) s = fmaf(ev[d], D[d][r], s);
                        nt[h * 4 + r] = bft(s);
                    }
                }
                tmpB = nt;
                e8c = e8n;
            }
            ring_l[t & (RING - 1)][lane] = tmpB;
            if (t & 1) {
                __threadfence_block();                      // commit ring writes
                if (lane == 0) *(volatile int*)&head_l = t + 1;
            }
            if ((t & 7) == 7 && t >= RING - 1 && t < 120) {
                // next 8 steps overwrite items t+1-RING..t+8-RING: need min(prog) >= t+9-RING
                const int need = t + 9 - RING;
                while (true) {
                    int p = (lane < 15) ? *(volatile int*)&prog_l[lane] : (1 << 30);
                    #pragma unroll
                    for (int s = 1; s < 64; s <<= 1) {
                        const int q = __shfl_xor(p, s, 64);
                        p = (q < p) ? q : p;
                    }
                    if (p >= need) break;
                    __builtin_amdgcn_s_sleep(4);
                }
            }
        }
        if (lane < 16) part_l[0][lane] = 0.f;
    } else {
        // ========================== CONSUMERS ==========================
        short8v W1f[4];    // h1 out = mt*16+col, k = th feature (permuted)
        #pragma unroll
        for (int mt = 0; mt < 4; ++mt)
            #pragma unroll
            for (int jj = 0; jj < 8; ++jj)
                W1f[mt][jj] = (short)bfr(n1w[((jj >> 2) * 16 + quad * 4 + (jj & 3)) * 64 + mt * 16 + col]);
        short8v W2f[4][2];
        #pragma unroll
        for (int mt = 0; mt < 4; ++mt)
            #pragma unroll
            for (int kb = 0; kb < 2; ++kb)
                #pragma unroll
                for (int jj = 0; jj < 8; ++jj)
                    W2f[mt][kb][jj] = (short)bfr(
                        n2w[(kb * 32 + (jj >> 2) * 16 + quad * 4 + (jj & 3)) * 64 + mt * 16 + col]);
        short8v Whf[3][2]; // 0=mu,1=sig,2=alpha; out m = head idx (col<10)
        #pragma unroll
        for (int mt = 0; mt < 3; ++mt) {
            const float* Wh = (mt == 0) ? muw : (mt == 1) ? sgw : alw;
            #pragma unroll
            for (int kb = 0; kb < 2; ++kb)
                #pragma unroll
                for (int jj = 0; jj < 8; ++jj)
                    Whf[mt][kb][jj] = (short)(col < 10
                        ? bfr(Wh[(kb * 32 + (jj >> 2) * 16 + quad * 4 + (jj & 3)) * 10 + col]) : 0);
        }

        float res2 = 0.f;
        const float CST = 0.91893853320467274f;
        const int c = wv - 1;

        int t;
        if (lane == 0) { t = atomicAdd(&ticket_l, 1); *(volatile int*)&prog_l[c] = t; }
        t = __shfl(t, 0, 64);

        while (t < TT) {
            // ACQUIRE: orders the ring read after the observed head bump,
            // in compiler and HW, without an all-memory asm clobber.
            while (__hip_atomic_load(&head_l, __ATOMIC_ACQUIRE,
                                     __HIP_MEMORY_SCOPE_WORKGROUP) <= t)
                __builtin_amdgcn_s_sleep(1);
            const short8v tf = ring_l[t & (RING - 1)][lane];
            __threadfence_block();           // ring read complete before prog bump
            int tn;
            if (lane == 0) { tn = atomicAdd(&ticket_l, 1); *(volatile int*)&prog_l[c] = tn; }
            tn = __shfl(tn, 0, 64);

            short8v thB;
            #pragma unroll
            for (int jj = 0; jj < 8; ++jj)
                thB[jj] = bft(ftanh(bf2f((unsigned short)tf[jj])));

            // h1 = relu(W1^T @ th + b1)   (bias as C operand)
            short8v h1B[2];
            #pragma unroll
            for (int mt = 0; mt < 4; ++mt) {
                const f32x4 cc = *(const f32x4*)&n1b_l[mt * 16 + quad * 4];
                const f32x4 d = MFMA32(W1f[mt], thB, cc);
                #pragma unroll
                for (int r = 0; r < 4; ++r)
                    h1B[mt >> 1][(mt & 1) * 4 + r] = bft(fmaxf(d[r], 0.f));
            }
            // h2 = relu(W2^T @ h1 + b2)
            short8v h2B[2];
            #pragma unroll
            for (int mt = 0; mt < 4; ++mt) {
                const f32x4 cc = *(const f32x4*)&n2b_l[mt * 16 + quad * 4];
                f32x4 d = MFMA32(W2f[mt][0], h1B[0], cc);
                d = MFMA32(W2f[mt][1], h1B[1], d);
                #pragma unroll
                for (int r = 0; r < 4; ++r)
                    h2B[mt >> 1][(mt & 1) * 4 + r] = bft(fmaxf(d[r], 0.f));
            }
            // heads; lane holds heads quad*4+r for sample col
            f32x4 hd[3];
            #pragma unroll
            for (int mt = 0; mt < 3; ++mt) {
                const f32x4 cc = *(const f32x4*)&hb_l[mt * 16 + quad * 4];
                f32x4 d = MFMA32(Whf[mt][0], h2B[0], cc);
                hd[mt] = MFMA32(Whf[mt][1], h2B[1], d);
            }
            // no-max logsumexp (terms O(1); underflow->0 == reference's 0)
            const float xt = x_l[col * 130 + t];
            float s1 = 0.f, s2 = 0.f;
            #pragma unroll
            for (int r = 0; r < 4; ++r) {
                const bool valid = (quad * 4 + r) < 10;
                const float mu = hd[0][r], sg = hd[1][r], la = hd[2][r];
                const float e1t = __expf(la);
                const float z = (xt - mu) * __expf(-sg);
                const float e2t = __expf(la - sg - fmaf(0.5f * z, z, CST));
                s1 += valid ? e1t : 0.f;
                s2 += valid ? e2t : 0.f;
            }
            s1 += __shfl_xor(s1, 16, 64);  s2 += __shfl_xor(s2, 16, 64);
            s1 += __shfl_xor(s1, 32, 64);  s2 += __shfl_xor(s2, 32, 64);
            res2 += __log2f(s2) - __log2f(s1);

            t = tn;
        }
        if (lane == 0) *(volatile int*)&prog_l[c] = 1 << 30;
        if (lane < 16) part_l[wv][lane] = res2;   // uniform across quads
    }

    __syncthreads();
    if (tid < 16) {
        float s = 0.f;
        #pragma unroll
        for (int w = 0; w < 16; ++w) s += part_l[w][tid];
        out[n0 + tid] = exp2f(s);
    }
}

extern "C" void kernel_launch(void* const* d_in, const int* in_sizes, int n_in,
                              void* d_out, int out_size, void* d_ws, size_t ws_size,
                              hipStream_t stream) {
    wfa_kernel<<<dim3(NN / 16), dim3(1024), 0, stream>>>(
        (const float*)d_in[0],  (const float*)d_in[1],  (const float*)d_in[2],
        (const float*)d_in[3],  (const float*)d_in[4],  (const float*)d_in[5],
        (const float*)d_in[6],  (const float*)d_in[7],  (const float*)d_in[8],
        (const float*)d_in[9],  (const float*)d_in[10], (const float*)d_in[11],
        (const float*)d_in[12], (const float*)d_in[13], (const float*)d_in[14],
        (const float*)d_in[15], (const float*)d_in[16], (float*)d_out);
}

// Round 4
// 148.581 us; speedup vs baseline: 1.1014x; 1.0495x over previous
//
#include <hip/hip_runtime.h>

#define DEV __device__ __forceinline__

typedef __attribute__((ext_vector_type(8))) short short8v;
typedef __attribute__((ext_vector_type(4))) float f32x4;

DEV unsigned short bfr(float f) {                 // fp32 -> bf16 RNE (weights)
    unsigned u = __float_as_uint(f);
    return (unsigned short)((u + 0x7fffu + ((u >> 16) & 1u)) >> 16);
}
DEV short bft(float f) { return (short)(__float_as_uint(f) >> 16); } // truncate (activations)
DEV float bf2f(unsigned short h) { return __uint_as_float(((unsigned)h) << 16); }
DEV float frcp(float x) { return __builtin_amdgcn_rcpf(x); }
DEV float ftanh(float x) { float e = __expf(2.0f * x); return 1.0f - 2.0f * frcp(e + 1.0f); }

constexpr int NN = 4096, TT = 128, RING = 32;
#define MFMA32(a, b, c) __builtin_amdgcn_mfma_f32_16x16x32_bf16(a, b, c, 0, 0, 0)

// Decoupled producer/consumer at the PROVEN register regime: 512 threads.
// R1-R3 LESSON: any 1024-thread build of this code gets a hard 64-VGPR cap
// (attributes amdgpu_waves_per_eu(4)/(4,4) and LDS padding all failed to
// lift it) -> ~45MB/dispatch scratch spills -> 80us. At 512 threads R0
// compiled the same per-wave code to 84 VGPR, WRITE_SIZE 16KB. So: keep the
// validated lock-free structure (3 passing rounds), drop to 8 waves.
//   Wave 0 (scanner): free-runs the 127-step serial tmp recurrence,
//   publishing bf16 tmp B-frags to a 32-slot LDS ring; fence + head bump
//   every 2 steps; every 8 steps polls per-consumer progress before slot
//   reuse (consumers may lag up to 24 items).
//   Waves 1-7 (consumers): pull items by LDS-atomic ticket (dynamic balance
//   absorbs the SIMD0 wave that shares issue with the scanner), ACQUIRE-poll
//   head, read frag, bump prog, run phi. NO mid-kernel barriers, NO asm
//   memory clobbers (R2 lesson: clobber in hot loop re-triggered scratch).

__global__ __launch_bounds__(512) __attribute__((amdgpu_waves_per_eu(2)))
void wfa_kernel(
    const float* __restrict__ x,
    const float* __restrict__ e1w, const float* __restrict__ e1b,
    const float* __restrict__ e2w, const float* __restrict__ e2b,
    const float* __restrict__ A,
    const float* __restrict__ initw,
    const float* __restrict__ n1w, const float* __restrict__ n1b,
    const float* __restrict__ n2w, const float* __restrict__ n2b,
    const float* __restrict__ muw, const float* __restrict__ mub,
    const float* __restrict__ sgw, const float* __restrict__ sgb,
    const float* __restrict__ alw, const float* __restrict__ alb,
    float* __restrict__ out)
{
    __shared__ __align__(16) unsigned short enc_l[TT * 128];  // [t][n*8+d] bf16, 32KB
    __shared__ __align__(16) float x_l[16 * 130];             // [n][t]
    __shared__ __align__(16) short8v ring_l[RING][64];        // tmp frags, 32KB
    __shared__ __align__(16) float n1b_l[64], n2b_l[64], hb_l[48];
    __shared__ float part_l[8][16];
    __shared__ int head_l;     // items published by scanner
    __shared__ int ticket_l;   // next item index to hand out
    __shared__ int prog_l[7];  // per-consumer: all my ring reads < prog are done

    const int tid = threadIdx.x;
    const int wv = tid >> 6, lane = tid & 63;
    const int quad = lane >> 4, col = lane & 15;
    const int n0 = blockIdx.x * 16;
    const f32x4 z4 = {0.f, 0.f, 0.f, 0.f};

    // ---- stage x + biases + control ----
    for (int i = tid; i < 16 * TT; i += 512)
        x_l[(i >> 7) * 130 + (i & 127)] = x[(n0 + (i >> 7)) * TT + (i & 127)];
    if (tid < 64) { n1b_l[tid] = n1b[tid]; n2b_l[tid] = n2b[tid]; }
    if (tid >= 64 && tid < 112) {
        const int i = tid - 64, mt = i >> 4, k = i & 15;
        hb_l[i] = (k < 10) ? ((mt == 0) ? mub[k] : (mt == 1) ? sgb[k] : alb[k]) : 0.f;
    }
    if (tid >= 112 && tid < 119) prog_l[tid - 112] = 0;
    if (tid == 120) { head_l = 0; ticket_l = 0; }

    __syncthreads();   // x_l + control ready

    // ---- encoder: in-lane rank-1 layer1 + 2 MFMAs; wave wv owns t-tile wv ----
    {
        float e1c[16], e1bc[16];
        #pragma unroll
        for (int kc = 0; kc < 2; ++kc)
            #pragma unroll
            for (int jj = 0; jj < 8; ++jj) {
                const int f = kc * 32 + (jj >> 2) * 16 + quad * 4 + (jj & 3);
                e1c[kc * 8 + jj] = e1w[f];
                e1bc[kc * 8 + jj] = e1b[f];
            }
        short8v E2A[2];   // A[m=d(col<8)][k=h feature, permuted]
        #pragma unroll
        for (int kc = 0; kc < 2; ++kc)
            #pragma unroll
            for (int jj = 0; jj < 8; ++jj)
                E2A[kc][jj] = (short)(col < 8
                    ? bfr(e2w[(kc * 32 + (jj >> 2) * 16 + quad * 4 + (jj & 3)) * 8 + col]) : 0);
        float e2bc[4];
        #pragma unroll
        for (int r = 0; r < 4; ++r) e2bc[r] = (quad < 2) ? e2b[quad * 4 + r] : 0.f;

        const int tbase = wv * 16;
        #pragma unroll 1
        for (int nn = 0; nn < 16; ++nn) {
            const float xs = x_l[nn * 130 + tbase + col];
            short8v eB[2];
            #pragma unroll
            for (int kc = 0; kc < 2; ++kc)
                #pragma unroll
                for (int jj = 0; jj < 8; ++jj)
                    eB[kc][jj] = bft(fmaxf(fmaf(xs, e1c[kc * 8 + jj], e1bc[kc * 8 + jj]), 0.f));
            f32x4 d = MFMA32(E2A[0], eB[0], z4);
            d = MFMA32(E2A[1], eB[1], d);
            if (quad < 2) {
                #pragma unroll
                for (int r = 0; r < 4; ++r)
                    enc_l[(tbase + col) * 128 + nn * 8 + quad * 4 + r] = bfr(ftanh(d[r] + e2bc[r]));
            }
        }
    }
    __syncthreads();   // enc_l ready; last block-wide barrier until epilogue

    if (wv == 0) {
        // =========================== SCANNER ===========================
        short8v A2f[16];   // out m=mt*16+col -> d=mt>>1, j-half=mt&1; k=i (permuted)
        #pragma unroll
        for (int mt = 0; mt < 16; ++mt)
            #pragma unroll
            for (int jj = 0; jj < 8; ++jj)
                A2f[mt][jj] = (short)bfr(
                    A[((jj >> 2) * 16 + quad * 4 + (jj & 3)) * 256 + (mt >> 1) * 32 + (mt & 1) * 16 + col]);

        short8v tmpB;
        #pragma unroll
        for (int jj = 0; jj < 8; ++jj)
            tmpB[jj] = (short)bfr(initw[(jj >> 2) * 16 + quad * 4 + (jj & 3)]);

        asm volatile("s_setprio 2");   // win SIMD0 arbitration vs co-resident consumer

        short8v e8c = *(const short8v*)&enc_l[0 * 128 + col * 8];  // enc[0] for t=1

        #pragma unroll 1
        for (int t = 0; t < TT; ++t) {
            if (t > 0) {
                // prefetch enc[t] (used at t+1); waited only at e8c=e8n
                const short8v e8n = *(const short8v*)&enc_l[t * 128 + col * 8];
                float ev[8];
                #pragma unroll
                for (int d = 0; d < 8; ++d) ev[d] = bf2f((unsigned short)e8c[d]);
                short8v nt;
                #pragma unroll
                for (int h = 0; h < 2; ++h) {
                    f32x4 D[8];
                    #pragma unroll
                    for (int d = 0; d < 8; ++d) D[d] = MFMA32(A2f[2 * d + h], tmpB, z4);
                    #pragma unroll
                    for (int r = 0; r < 4; ++r) {
                        float s = 0.f;
                        #pragma unroll
                        for (int d = 0; d < 8; ++d) s = fmaf(ev[d], D[d][r], s);
                        nt[h * 4 + r] = bft(s);
                    }
                }
                tmpB = nt;
                e8c = e8n;
            }
            ring_l[t & (RING - 1)][lane] = tmpB;
            if (t & 1) {
                __threadfence_block();                      // commit ring writes
                if (lane == 0) *(volatile int*)&head_l = t + 1;
            }
            if ((t & 7) == 7 && t >= RING - 1 && t < 120) {
                // next 8 writes hit slots of items t+1-RING..t+8-RING:
                // need min(prog) >= t+9-RING
                const int need = t + 9 - RING;
                while (true) {
                    int p = (lane < 7) ? *(volatile int*)&prog_l[lane] : (1 << 30);
                    #pragma unroll
                    for (int s = 1; s < 64; s <<= 1) {
                        const int q = __shfl_xor(p, s, 64);
                        p = (q < p) ? q : p;
                    }
                    if (p >= need) break;
                    __builtin_amdgcn_s_sleep(4);
                }
            }
        }
        if (lane < 16) part_l[0][lane] = 0.f;
    } else {
        // ========================== CONSUMERS ==========================
        short8v W1f[4];    // h1 out = mt*16+col, k = th feature (permuted)
        #pragma unroll
        for (int mt = 0; mt < 4; ++mt)
            #pragma unroll
            for (int jj = 0; jj < 8; ++jj)
                W1f[mt][jj] = (short)bfr(n1w[((jj >> 2) * 16 + quad * 4 + (jj & 3)) * 64 + mt * 16 + col]);
        short8v W2f[4][2];
        #pragma unroll
        for (int mt = 0; mt < 4; ++mt)
            #pragma unroll
            for (int kb = 0; kb < 2; ++kb)
                #pragma unroll
                for (int jj = 0; jj < 8; ++jj)
                    W2f[mt][kb][jj] = (short)bfr(
                        n2w[(kb * 32 + (jj >> 2) * 16 + quad * 4 + (jj & 3)) * 64 + mt * 16 + col]);
        short8v Whf[3][2]; // 0=mu,1=sig,2=alpha; out m = head idx (col<10)
        #pragma unroll
        for (int mt = 0; mt < 3; ++mt) {
            const float* Wh = (mt == 0) ? muw : (mt == 1) ? sgw : alw;
            #pragma unroll
            for (int kb = 0; kb < 2; ++kb)
                #pragma unroll
                for (int jj = 0; jj < 8; ++jj)
                    Whf[mt][kb][jj] = (short)(col < 10
                        ? bfr(Wh[(kb * 32 + (jj >> 2) * 16 + quad * 4 + (jj & 3)) * 10 + col]) : 0);
        }

        float res2 = 0.f;
        const float CST = 0.91893853320467274f;
        const int c = wv - 1;

        int t;
        if (lane == 0) { t = atomicAdd(&ticket_l, 1); *(volatile int*)&prog_l[c] = t; }
        t = __shfl(t, 0, 64);

        while (t < TT) {
            // ACQUIRE: orders the ring read after the observed head bump,
            // in compiler and HW, without an all-memory asm clobber.
            while (__hip_atomic_load(&head_l, __ATOMIC_ACQUIRE,
                                     __HIP_MEMORY_SCOPE_WORKGROUP) <= t)
                __builtin_amdgcn_s_sleep(1);
            const short8v tf = ring_l[t & (RING - 1)][lane];
            __threadfence_block();           // ring read complete before prog bump
            int tn;
            if (lane == 0) { tn = atomicAdd(&ticket_l, 1); *(volatile int*)&prog_l[c] = tn; }
            tn = __shfl(tn, 0, 64);

            short8v thB;
            #pragma unroll
            for (int jj = 0; jj < 8; ++jj)
                thB[jj] = bft(ftanh(bf2f((unsigned short)tf[jj])));

            // h1 = relu(W1^T @ th + b1)   (bias as C operand)
            short8v h1B[2];
            #pragma unroll
            for (int mt = 0; mt < 4; ++mt) {
                const f32x4 cc = *(const f32x4*)&n1b_l[mt * 16 + quad * 4];
                const f32x4 d = MFMA32(W1f[mt], thB, cc);
                #pragma unroll
                for (int r = 0; r < 4; ++r)
                    h1B[mt >> 1][(mt & 1) * 4 + r] = bft(fmaxf(d[r], 0.f));
            }
            // h2 = relu(W2^T @ h1 + b2)
            short8v h2B[2];
            #pragma unroll
            for (int mt = 0; mt < 4; ++mt) {
                const f32x4 cc = *(const f32x4*)&n2b_l[mt * 16 + quad * 4];
                f32x4 d = MFMA32(W2f[mt][0], h1B[0], cc);
                d = MFMA32(W2f[mt][1], h1B[1], d);
                #pragma unroll
                for (int r = 0; r < 4; ++r)
                    h2B[mt >> 1][(mt & 1) * 4 + r] = bft(fmaxf(d[r], 0.f));
            }
            // heads; lane holds heads quad*4+r for sample col
            f32x4 hd[3];
            #pragma unroll
            for (int mt = 0; mt < 3; ++mt) {
                const f32x4 cc = *(const f32x4*)&hb_l[mt * 16 + quad * 4];
                f32x4 d = MFMA32(Whf[mt][0], h2B[0], cc);
                hd[mt] = MFMA32(Whf[mt][1], h2B[1], d);
            }
            // no-max logsumexp (terms O(1); underflow->0 == reference's 0)
            const float xt = x_l[col * 130 + t];
            float s1 = 0.f, s2 = 0.f;
            #pragma unroll
            for (int r = 0; r < 4; ++r) {
                const bool valid = (quad * 4 + r) < 10;
                const float mu = hd[0][r], sg = hd[1][r], la = hd[2][r];
                const float e1t = __expf(la);
                const float z = (xt - mu) * __expf(-sg);
                const float e2t = __expf(la - sg - fmaf(0.5f * z, z, CST));
                s1 += valid ? e1t : 0.f;
                s2 += valid ? e2t : 0.f;
            }
            s1 += __shfl_xor(s1, 16, 64);  s2 += __shfl_xor(s2, 16, 64);
            s1 += __shfl_xor(s1, 32, 64);  s2 += __shfl_xor(s2, 32, 64);
            res2 += __log2f(s2) - __log2f(s1);

            t = tn;
        }
        if (lane == 0) *(volatile int*)&prog_l[c] = 1 << 30;
        if (lane < 16) part_l[wv][lane] = res2;   // uniform across quads
    }

    __syncthreads();
    if (tid < 16) {
        float s = 0.f;
        #pragma unroll
        for (int w = 0; w < 8; ++w) s += part_l[w][tid];
        out[n0 + tid] = exp2f(s);
    }
}

extern "C" void kernel_launch(void* const* d_in, const int* in_sizes, int n_in,
                              void* d_out, int out_size, void* d_ws, size_t ws_size,
                              hipStream_t stream) {
    wfa_kernel<<<dim3(NN / 16), dim3(512), 0, stream>>>(
        (const float*)d_in[0],  (const float*)d_in[1],  (const float*)d_in[2],
        (const float*)d_in[3],  (const float*)d_in[4],  (const float*)d_in[5],
        (const float*)d_in[6],  (const float*)d_in[7],  (const float*)d_in[8],
        (const float*)d_in[9],  (const float*)d_in[10], (const float*)d_in[11],
        (const float*)d_in[12], (const float*)d_in[13], (const float*)d_in[14],
        (const float*)d_in[15], (const float*)d_in[16], (float*)d_out);
}